// Round 5
// baseline (622.743 us; speedup 1.0000x reference)
//
#include <hip/hip_runtime.h>
#include <cstdint>
#include <cstddef>

typedef unsigned short u16;
typedef __attribute__((ext_vector_type(8))) short bf16x8;
typedef __attribute__((ext_vector_type(4))) float f32x4;
typedef __attribute__((ext_vector_type(16))) float f32x16;
typedef __attribute__((ext_vector_type(4))) unsigned short u16x4;

#define DEV static __device__ __forceinline__

DEV u16 f2bf(float f) {
  union { float f; uint32_t u; } c; c.f = f;
  uint32_t u = c.u;
  return (u16)((u + 0x7fffu + ((u >> 16) & 1u)) >> 16);
}

DEV void gload16(const void* g, void* l) {
  __builtin_amdgcn_global_load_lds((const __attribute__((address_space(1))) void*)g,
                                   (__attribute__((address_space(3))) void*)l, 16, 0, 0);
}

// ---------------- weight convert + transpose: W f32 [K,N] -> Wt bf16 [N,K] * scale
__global__ __launch_bounds__(256)
void wconv_kernel(const float* __restrict__ W, u16* __restrict__ Wt, int K, int N,
                  float scale) {
  __shared__ float tile[32][33];
  const int k0 = blockIdx.y << 5;
  const int n0 = blockIdx.x << 5;
  const int c  = threadIdx.x & 31;
  const int r0 = threadIdx.x >> 5;
#pragma unroll
  for (int i = 0; i < 4; i++) {
    int r = r0 + i * 8;
    tile[r][c] = W[(size_t)(k0 + r) * N + n0 + c];
  }
  __syncthreads();
#pragma unroll
  for (int i = 0; i < 4; i++) {
    int r = r0 + i * 8;
    Wt[(size_t)(n0 + r) * K + k0 + c] = f2bf(tile[c][r] * scale);
  }
}

// ---------------- bias concat: bq*SC|bk|bv -> bqkv[3072] --------------------------
__global__ void bcat_kernel(const float* __restrict__ bq, const float* __restrict__ bk,
                            const float* __restrict__ bv, float* __restrict__ o,
                            float sc) {
  int i = blockIdx.x * 256 + threadIdx.x;
  float v = (i < 1024) ? bq[i] * sc : (i < 2048 ? bk[i - 1024] : bv[i - 2048]);
  o[i] = v;
}

// ---------------- LayerNorm: f32 [M,1024] -> bf16 [M,1024] ------------------------
__global__ __launch_bounds__(256)
void ln_kernel(const float* __restrict__ x, const float* __restrict__ w,
               const float* __restrict__ b, u16* __restrict__ out) {
  const int row = blockIdx.x;
  const int t = threadIdx.x;
  __shared__ float red[4];
  const float4 v = ((const float4*)(x + (size_t)row * 1024))[t];
  float s = v.x + v.y + v.z + v.w;
#pragma unroll
  for (int off = 32; off; off >>= 1) s += __shfl_xor(s, off);
  if ((t & 63) == 0) red[t >> 6] = s;
  __syncthreads();
  const float mu = (red[0] + red[1] + red[2] + red[3]) * (1.0f / 1024.0f);
  __syncthreads();
  float dx = v.x - mu, dy = v.y - mu, dz = v.z - mu, dw = v.w - mu;
  float ss = dx * dx + dy * dy + dz * dz + dw * dw;
#pragma unroll
  for (int off = 32; off; off >>= 1) ss += __shfl_xor(ss, off);
  if ((t & 63) == 0) red[t >> 6] = ss;
  __syncthreads();
  const float var = (red[0] + red[1] + red[2] + red[3]) * (1.0f / 1024.0f);
  const float rstd = rsqrtf(var + 1e-5f);
  const float4 wv = ((const float4*)w)[t];
  const float4 bv = ((const float4*)b)[t];
  u16x4 o;
  o[0] = f2bf(dx * rstd * wv.x + bv.x);
  o[1] = f2bf(dy * rstd * wv.y + bv.y);
  o[2] = f2bf(dz * rstd * wv.z + bv.z);
  o[3] = f2bf(dw * rstd * wv.w + bv.w);
  *((u16x4*)(out + (size_t)row * 1024 + t * 4)) = o;
}

// ---------------- GEMM: A bf16 [M,K] @ Bt bf16 [N,K] + bias, m97 structure --------
template <bool RELU, bool RESID>
__global__ __launch_bounds__(256, 2)
void gemm_kernel(const u16* __restrict__ A, const u16* __restrict__ Bt,
                 const float* __restrict__ bias, const float* __restrict__ resid,
                 u16* __restrict__ outb, float* __restrict__ outf,
                 int M, int N, int K) {
  __shared__ short As[128 * 64];
  __shared__ short Bs[128 * 64];
  const int l = threadIdx.x & 63;
  const int w = threadIdx.x >> 6;
  const int m0 = blockIdx.y * 128;
  const int n0 = blockIdx.x * 128;
  const int mw = (w >> 1) * 64;
  const int nw = (w & 1) * 64;

  f32x4 acc[4][4];
#pragma unroll
  for (int i = 0; i < 4; i++)
#pragma unroll
    for (int j = 0; j < 4; j++) acc[i][j] = {0.f, 0.f, 0.f, 0.f};

  const int nk = K >> 6;
  for (int kt = 0; kt < nk; ++kt) {
    const int k0 = kt << 6;
#pragma unroll
    for (int i = 0; i < 4; i++) {
      int o = ((w * 4 + i) << 10) + l * 16;  // byte offset in 16KB tile
      int row = o >> 7;                      // 128B per row (64 bf16)
      int ke = (o & 127) >> 1;               // element col
      gload16(A + (size_t)(m0 + row) * K + k0 + ke, (short*)As + ((w * 4 + i) << 9));
      gload16(Bt + (size_t)(n0 + row) * K + k0 + ke, (short*)Bs + ((w * 4 + i) << 9));
    }
    __syncthreads();
#pragma unroll
    for (int kg = 0; kg < 2; ++kg) {
      bf16x8 af[4], bfr[4];
#pragma unroll
      for (int i = 0; i < 4; i++) {
        af[i]  = *(const bf16x8*)(As + (mw + i * 16 + (l & 15)) * 64 + kg * 32 + (l >> 4) * 8);
        bfr[i] = *(const bf16x8*)(Bs + (nw + i * 16 + (l & 15)) * 64 + kg * 32 + (l >> 4) * 8);
      }
#pragma unroll
      for (int i = 0; i < 4; i++)
#pragma unroll
        for (int j = 0; j < 4; j++)
          acc[i][j] = __builtin_amdgcn_mfma_f32_16x16x32_bf16(af[i], bfr[j], acc[i][j], 0, 0, 0);
    }
    __syncthreads();
  }

#pragma unroll
  for (int i = 0; i < 4; i++) {
    const int r0 = m0 + mw + i * 16 + ((l >> 4) << 2);
#pragma unroll
    for (int j = 0; j < 4; j++) {
      const int c = n0 + nw + j * 16 + (l & 15);
      const float bb = bias[c];
#pragma unroll
      for (int r = 0; r < 4; r++) {
        float v = acc[i][j][r] + bb;
        if (RELU) v = fmaxf(v, 0.0f);
        const size_t idx = (size_t)(r0 + r) * N + c;
        if (RESID)
          outf[idx] = resid[idx] + v;
        else
          outb[idx] = f2bf(v);
      }
    }
  }
}

// ---------------- V transpose: qkv V-cols -> Vt_g[bh*64+d][t] ---------------------
__global__ __launch_bounds__(256)
void vtrans_kernel(const u16* __restrict__ QKV, u16* __restrict__ Vt_g) {
  __shared__ u16 tile[32][33];
  const int t0 = blockIdx.x * 32;
  const int d0 = blockIdx.y * 32;
  const int bh = blockIdx.z;
  const int bb = bh >> 4, hh = bh & 15;
  const int c = threadIdx.x & 31, r0 = threadIdx.x >> 5;
#pragma unroll
  for (int i = 0; i < 4; i++) {
    int r = r0 + i * 8;
    tile[r][c] = QKV[(size_t)(bb * 2048 + t0 + r) * 3072 + 2048 + hh * 64 + d0 + c];
  }
  __syncthreads();
#pragma unroll
  for (int i = 0; i < 4; i++) {
    int r = r0 + i * 8;
    Vt_g[((size_t)bh * 64 + d0 + r) * 2048 + t0 + c] = tile[c][r];
  }
}

// ---------------- causal flash attention, 64-row q-blocks, 2 waves, swapped -------
// S[k][q] = mfma(Kfrag, Qfrag); Q pre-scaled by 0.125*log2(e) (folded into Wq/bq);
// softmax lane-local (q = lane&31), defer-max (THR=8); P in regs via cvt_pk +
// permlane32_swap; Y^T-basis PV: mfma(Vt, P).
__global__ __launch_bounds__(128, 2)
void attn_kernel(const u16* __restrict__ QKV, const u16* __restrict__ Vt_g,
                 u16* __restrict__ Y) {
  __shared__ short Ks[2][64 * 64];
  __shared__ short Vs[2][64 * 64];
  const int tid = threadIdx.x;
  const int l = tid & 63;
  const int w = tid >> 6;              // 0..1
  const int lane31 = l & 31;
  const int khalf = l >> 5;
  const int qt = gridDim.x - 1 - blockIdx.x;   // descending: long blocks first
  const int bh = blockIdx.y;
  const int bb = bh >> 4, hh = bh & 15;
  const size_t baseT = (size_t)bb * 2048;
  const int qrel = qt * 64 + w * 32 + lane31;  // q index within this (b,h)
  const size_t qrow = baseT + qrel;

  // Q fragments (B-operand), hoisted: q = lane31, k = s*16 + khalf*8 + e
  bf16x8 qf[4];
  {
    const u16* qp = QKV + qrow * 3072 + hh * 64 + khalf * 8;
#pragma unroll
    for (int s = 0; s < 4; s++) qf[s] = *(const bf16x8*)(qp + s * 16);
  }

  f32x16 yac0, yac1;   // Y^T basis: row d = (reg&3)+8*(reg>>2)+4*khalf (+32), col q = lane31
#pragma unroll
  for (int i = 0; i < 16; i++) { yac0[i] = 0.f; yac1[i] = 0.f; }
  float m_ = -INFINITY, s_ = 0.f;

  auto stage = [&](int j, int buf) {
    const u16* kb = QKV + (baseT + j * 64) * 3072 + 1024 + hh * 64;
    const u16* vb = Vt_g + (size_t)bh * 64 * 2048 + j * 64;
#pragma unroll
    for (int i = 0; i < 4; i++) {
      int idx = i * 128 + tid;               // 16B slot: row = idx>>3, colblock = idx&7
      int row = idx >> 3, cb = idx & 7;
      int cbs = (cb ^ (row & 7)) * 8;        // pre-swizzled global source (rule 21)
      gload16(kb + (size_t)row * 3072 + cbs, &Ks[buf][(i * 128 + w * 64) * 8]);
      gload16(vb + (size_t)row * 2048 + cbs, &Vs[buf][(i * 128 + w * 64) * 8]);
    }
  };

  const int jmax = qt;
  stage(0, 0);
  __syncthreads();
  int cur = 0;
  for (int j = 0; j <= jmax; ++j) {
    if (j < jmax) stage(j + 1, cur ^ 1);
    const short* Kc = Ks[cur];
    const short* Vc = Vs[cur];

    // ---- QK^T (swapped): S[k][q], k-halves ----
    f32x16 sa0, sa1;
#pragma unroll
    for (int i = 0; i < 16; i++) { sa0[i] = 0.f; sa1[i] = 0.f; }
    __builtin_amdgcn_s_setprio(1);
#pragma unroll
    for (int s = 0; s < 4; s++) {
      int cb = ((s * 2 + khalf) ^ (l & 7)) * 8;   // swizzled read
      bf16x8 k0 = *(const bf16x8*)(Kc + lane31 * 64 + cb);
      bf16x8 k1 = *(const bf16x8*)(Kc + (32 + lane31) * 64 + cb);
      sa0 = __builtin_amdgcn_mfma_f32_32x32x16_bf16(k0, qf[s], sa0, 0, 0, 0);
      sa1 = __builtin_amdgcn_mfma_f32_32x32x16_bf16(k1, qf[s], sa1, 0, 0, 0);
    }
    __builtin_amdgcn_s_setprio(0);

    // ---- mask + online softmax (lane-local rows, partner = l^32), log2 domain ----
    float p0[16], p1[16];
    float tmax = -INFINITY;
    const bool bnd = (j == qt);
#pragma unroll
    for (int r = 0; r < 16; r++) {
      float v0 = sa0[r], v1 = sa1[r];
      if (bnd) {
        int kg = j * 64 + 4 * khalf + (r & 3) + 8 * (r >> 2);
        if (kg > qrel) v0 = -INFINITY;
        if (kg + 32 > qrel) v1 = -INFINITY;
      }
      p0[r] = v0; p1[r] = v1;
      tmax = fmaxf(tmax, fmaxf(v0, v1));
    }
    tmax = fmaxf(tmax, __shfl_xor(tmax, 32));
    // defer-max (T13): only rescale when the running max moved by > 8 (2^8 headroom)
    if (!__all(tmax - m_ <= 8.0f)) {
      const float nm = fmaxf(m_, tmax);
      const float alpha = exp2f(m_ - nm);
      m_ = nm;
      s_ *= alpha;
#pragma unroll
      for (int i = 0; i < 16; i++) { yac0[i] *= alpha; yac1[i] *= alpha; }
    }
    float sum = 0.f;
#pragma unroll
    for (int r = 0; r < 16; r++) {
      p0[r] = exp2f(p0[r] - m_);
      p1[r] = exp2f(p1[r] - m_);
      sum += p0[r] + p1[r];
    }
    sum += __shfl_xor(sum, 32);
    s_ += sum;

    // ---- pack P to bf16 dwords: pk{0,1}[jj], jj = kt*4 + rb/4 ----
    uint32_t pk0[8], pk1[8];
#pragma unroll
    for (int jj = 0; jj < 4; jj++) {
      int rb = 4 * jj;
      uint32_t a, b;
      asm("v_cvt_pk_bf16_f32 %0, %1, %2" : "=v"(a) : "v"(p0[rb]), "v"(p0[rb + 1]));
      asm("v_cvt_pk_bf16_f32 %0, %1, %2" : "=v"(b) : "v"(p0[rb + 2]), "v"(p0[rb + 3]));
      pk0[jj] = a; pk1[jj] = b;
    }
#pragma unroll
    for (int jj = 0; jj < 4; jj++) {
      int rb = 4 * jj;
      uint32_t a, b;
      asm("v_cvt_pk_bf16_f32 %0, %1, %2" : "=v"(a) : "v"(p1[rb]), "v"(p1[rb + 1]));
      asm("v_cvt_pk_bf16_f32 %0, %1, %2" : "=v"(b) : "v"(p1[rb + 2]), "v"(p1[rb + 3]));
      pk0[4 + jj] = a; pk1[4 + jj] = b;
    }

    // ---- PV: yac += mfma(Vt_frag, P_frag) over kv-slices ----
#pragma unroll
    for (int kvs = 0; kvs < 4; kvs++) {
      uint32_t x0 = pk0[2 * kvs], y0 = pk0[2 * kvs + 1];
      uint32_t x1 = pk1[2 * kvs], y1 = pk1[2 * kvs + 1];
      asm volatile("v_permlane32_swap_b32 %0, %1" : "+v"(x0), "+v"(y0));
      asm volatile("v_permlane32_swap_b32 %0, %1" : "+v"(x1), "+v"(y1));
      union { uint32_t u[4]; bf16x8 v; } pf;
      pf.u[0] = x0; pf.u[1] = x1; pf.u[2] = y0; pf.u[3] = y1;
      int cb = ((kvs * 2 + khalf) ^ (l & 7)) * 8;
      bf16x8 v0 = *(const bf16x8*)(Vc + lane31 * 64 + cb);
      bf16x8 v1 = *(const bf16x8*)(Vc + (32 + lane31) * 64 + cb);
      __builtin_amdgcn_s_setprio(1);
      yac0 = __builtin_amdgcn_mfma_f32_32x32x16_bf16(v0, pf.v, yac0, 0, 0, 0);
      yac1 = __builtin_amdgcn_mfma_f32_32x32x16_bf16(v1, pf.v, yac1, 0, 0, 0);
      __builtin_amdgcn_s_setprio(0);
    }
    __syncthreads();
    cur ^= 1;
  }

  // ---- epilogue: Y[q][d] = yac/s ----
  const float sinv = 1.0f / s_;
  u16* yp = Y + qrow * 1024 + hh * 64;
#pragma unroll
  for (int rq = 0; rq < 4; rq++) {
    u16x4 o0, o1;
#pragma unroll
    for (int e = 0; e < 4; e++) {
      o0[e] = f2bf(yac0[rq * 4 + e] * sinv);
      o1[e] = f2bf(yac1[rq * 4 + e] * sinv);
    }
    *(u16x4*)(yp + 8 * rq + 4 * khalf) = o0;
    *(u16x4*)(yp + 32 + 8 * rq + 4 * khalf) = o1;
  }
}

extern "C" void kernel_launch(void* const* d_in, const int* in_sizes, int n_in,
                              void* d_out, int out_size, void* d_ws, size_t ws_size,
                              hipStream_t stream) {
  const float* x    = (const float*)d_in[0];
  const float* ln1w = (const float*)d_in[1];
  const float* ln1b = (const float*)d_in[2];
  const float* Wq   = (const float*)d_in[3];
  const float* bq   = (const float*)d_in[4];
  const float* Wk   = (const float*)d_in[5];
  const float* bk   = (const float*)d_in[6];
  const float* Wv   = (const float*)d_in[7];
  const float* bv   = (const float*)d_in[8];
  const float* Wo   = (const float*)d_in[9];
  const float* bo   = (const float*)d_in[10];
  const float* ln2w = (const float*)d_in[11];
  const float* ln2b = (const float*)d_in[12];
  const float* W1   = (const float*)d_in[13];
  const float* b1   = (const float*)d_in[14];
  const float* W2   = (const float*)d_in[15];
  const float* b2   = (const float*)d_in[16];
  float* out = (float*)d_out;
  char* ws = (char*)d_ws;
  const size_t MB = 1ull << 20;
  const float SC = 0.125f * 1.44269504088896340736f;  // 1/sqrt(64) * log2(e)

  u16* h     = (u16*)(ws);              // [0,16) LN1 out
  u16* qkv   = (u16*)(ws + 16 * MB);    // [16,64) fused QKV out [8192][3072]
  u16* ff1   = (u16*)(ws);              // [0,64) overlay (h,qkv dead by FF1)
  u16* Vt_g  = (u16*)(ws + 64 * MB);    // [64,80) V^T per head [4096][2048]
  float* x1  = (float*)(ws + 64 * MB);  // [64,96) post-attn residual (after Vt_g dead)
  u16* y     = (u16*)(ws + 96 * MB);    // [96,112) attn out; reused as LN2 out
  u16* Wqkvt = (u16*)(ws + 112 * MB);   // [112,118) Wq|Wk|Wv transposed [3072][1024]
  u16* Wot   = (u16*)(ws + 118 * MB);   // [118,120)
  u16* W1t   = (u16*)(ws + 120 * MB);   // [120,128) [4096,1024]
  u16* W2t   = (u16*)(ws + 128 * MB);   // [128,136) [1024,4096]
  float* bqkv = (float*)(ws + 136 * MB);

  dim3 tb(256);
  wconv_kernel<<<dim3(32, 32), tb, 0, stream>>>(Wq, Wqkvt, 1024, 1024, SC);
  wconv_kernel<<<dim3(32, 32), tb, 0, stream>>>(Wk, Wqkvt + (1024u * 1024), 1024, 1024, 1.0f);
  wconv_kernel<<<dim3(32, 32), tb, 0, stream>>>(Wv, Wqkvt + (2048u * 1024), 1024, 1024, 1.0f);
  wconv_kernel<<<dim3(32, 32), tb, 0, stream>>>(Wo, Wot, 1024, 1024, 1.0f);
  wconv_kernel<<<dim3(128, 32), tb, 0, stream>>>(W1, W1t, 1024, 4096, 1.0f);
  wconv_kernel<<<dim3(32, 128), tb, 0, stream>>>(W2, W2t, 4096, 1024, 1.0f);
  bcat_kernel<<<dim3(12), tb, 0, stream>>>(bq, bk, bv, bqkv, SC);

  ln_kernel<<<8192, tb, 0, stream>>>(x, ln1w, ln1b, h);

  // fused QKV: [8192,1024] @ [3072,1024]^T -> [8192,3072]
  gemm_kernel<false, false><<<dim3(24, 64), tb, 0, stream>>>(h, Wqkvt, bqkv, nullptr, qkv, nullptr, 8192, 3072, 1024);

  vtrans_kernel<<<dim3(64, 2, 64), tb, 0, stream>>>(qkv, Vt_g);

  attn_kernel<<<dim3(32, 64), dim3(128), 0, stream>>>(qkv, Vt_g, y);

  gemm_kernel<false, true><<<dim3(8, 64), tb, 0, stream>>>(y, Wot, bo, x, nullptr, x1, 8192, 1024, 1024);

  ln_kernel<<<8192, tb, 0, stream>>>(x1, ln2w, ln2b, y);

  gemm_kernel<true, false><<<dim3(32, 64), tb, 0, stream>>>(y, W1t, b1, nullptr, ff1, nullptr, 8192, 4096, 1024);

  gemm_kernel<false, true><<<dim3(8, 64), tb, 0, stream>>>(ff1, W2t, b2, x1, nullptr, out, 8192, 1024, 4096);
}

// Round 6
// 531.622 us; speedup vs baseline: 1.1714x; 1.1714x over previous
//
#include <hip/hip_runtime.h>
#include <cstdint>
#include <cstddef>

typedef unsigned short u16;
typedef __attribute__((ext_vector_type(8))) short bf16x8;
typedef __attribute__((ext_vector_type(4))) float f32x4;
typedef __attribute__((ext_vector_type(16))) float f32x16;
typedef __attribute__((ext_vector_type(4))) unsigned short u16x4;

#define DEV static __device__ __forceinline__

DEV u16 f2bf(float f) {
  union { float f; uint32_t u; } c; c.f = f;
  uint32_t u = c.u;
  return (u16)((u + 0x7fffu + ((u >> 16) & 1u)) >> 16);
}

DEV void gload16(const void* g, void* l) {
  __builtin_amdgcn_global_load_lds((const __attribute__((address_space(1))) void*)g,
                                   (__attribute__((address_space(3))) void*)l, 16, 0, 0);
}

// ---------------- weight convert + transpose: W f32 [K,N] -> Wt bf16 [N,K] * scale
__global__ __launch_bounds__(256)
void wconv_kernel(const float* __restrict__ W, u16* __restrict__ Wt, int K, int N,
                  float scale) {
  __shared__ float tile[32][33];
  const int k0 = blockIdx.y << 5;
  const int n0 = blockIdx.x << 5;
  const int c  = threadIdx.x & 31;
  const int r0 = threadIdx.x >> 5;
#pragma unroll
  for (int i = 0; i < 4; i++) {
    int r = r0 + i * 8;
    tile[r][c] = W[(size_t)(k0 + r) * N + n0 + c];
  }
  __syncthreads();
#pragma unroll
  for (int i = 0; i < 4; i++) {
    int r = r0 + i * 8;
    Wt[(size_t)(n0 + r) * K + k0 + c] = f2bf(tile[c][r] * scale);
  }
}

// ---------------- bias concat: bq*SC|bk|bv -> bqkv[3072] --------------------------
__global__ void bcat_kernel(const float* __restrict__ bq, const float* __restrict__ bk,
                            const float* __restrict__ bv, float* __restrict__ o,
                            float sc) {
  int i = blockIdx.x * 256 + threadIdx.x;
  float v = (i < 1024) ? bq[i] * sc : (i < 2048 ? bk[i - 1024] : bv[i - 2048]);
  o[i] = v;
}

// ---------------- LayerNorm: f32 [M,1024] -> bf16 [M,1024] ------------------------
__global__ __launch_bounds__(256)
void ln_kernel(const float* __restrict__ x, const float* __restrict__ w,
               const float* __restrict__ b, u16* __restrict__ out) {
  const int row = blockIdx.x;
  const int t = threadIdx.x;
  __shared__ float red[4];
  const float4 v = ((const float4*)(x + (size_t)row * 1024))[t];
  float s = v.x + v.y + v.z + v.w;
#pragma unroll
  for (int off = 32; off; off >>= 1) s += __shfl_xor(s, off);
  if ((t & 63) == 0) red[t >> 6] = s;
  __syncthreads();
  const float mu = (red[0] + red[1] + red[2] + red[3]) * (1.0f / 1024.0f);
  __syncthreads();
  float dx = v.x - mu, dy = v.y - mu, dz = v.z - mu, dw = v.w - mu;
  float ss = dx * dx + dy * dy + dz * dz + dw * dw;
#pragma unroll
  for (int off = 32; off; off >>= 1) ss += __shfl_xor(ss, off);
  if ((t & 63) == 0) red[t >> 6] = ss;
  __syncthreads();
  const float var = (red[0] + red[1] + red[2] + red[3]) * (1.0f / 1024.0f);
  const float rstd = rsqrtf(var + 1e-5f);
  const float4 wv = ((const float4*)w)[t];
  const float4 bv = ((const float4*)b)[t];
  u16x4 o;
  o[0] = f2bf(dx * rstd * wv.x + bv.x);
  o[1] = f2bf(dy * rstd * wv.y + bv.y);
  o[2] = f2bf(dz * rstd * wv.z + bv.z);
  o[3] = f2bf(dw * rstd * wv.w + bv.w);
  *((u16x4*)(out + (size_t)row * 1024 + t * 4)) = o;
}

// ---------------- GEMM: A bf16 [M,K] @ Bt bf16 [N,K] + bias, m97 structure --------
template <bool RELU, bool RESID>
__global__ __launch_bounds__(256, 2)
void gemm_kernel(const u16* __restrict__ A, const u16* __restrict__ Bt,
                 const float* __restrict__ bias, const float* __restrict__ resid,
                 u16* __restrict__ outb, float* __restrict__ outf,
                 int M, int N, int K) {
  __shared__ short As[128 * 64];
  __shared__ short Bs[128 * 64];
  const int l = threadIdx.x & 63;
  const int w = threadIdx.x >> 6;
  const int m0 = blockIdx.y * 128;
  const int n0 = blockIdx.x * 128;
  const int mw = (w >> 1) * 64;
  const int nw = (w & 1) * 64;

  f32x4 acc[4][4];
#pragma unroll
  for (int i = 0; i < 4; i++)
#pragma unroll
    for (int j = 0; j < 4; j++) acc[i][j] = {0.f, 0.f, 0.f, 0.f};

  const int nk = K >> 6;
  for (int kt = 0; kt < nk; ++kt) {
    const int k0 = kt << 6;
#pragma unroll
    for (int i = 0; i < 4; i++) {
      int o = ((w * 4 + i) << 10) + l * 16;  // byte offset in 16KB tile
      int row = o >> 7;                      // 128B per row (64 bf16)
      int ke = (o & 127) >> 1;               // element col
      gload16(A + (size_t)(m0 + row) * K + k0 + ke, (short*)As + ((w * 4 + i) << 9));
      gload16(Bt + (size_t)(n0 + row) * K + k0 + ke, (short*)Bs + ((w * 4 + i) << 9));
    }
    __syncthreads();
#pragma unroll
    for (int kg = 0; kg < 2; ++kg) {
      bf16x8 af[4], bfr[4];
#pragma unroll
      for (int i = 0; i < 4; i++) {
        af[i]  = *(const bf16x8*)(As + (mw + i * 16 + (l & 15)) * 64 + kg * 32 + (l >> 4) * 8);
        bfr[i] = *(const bf16x8*)(Bs + (nw + i * 16 + (l & 15)) * 64 + kg * 32 + (l >> 4) * 8);
      }
#pragma unroll
      for (int i = 0; i < 4; i++)
#pragma unroll
        for (int j = 0; j < 4; j++)
          acc[i][j] = __builtin_amdgcn_mfma_f32_16x16x32_bf16(af[i], bfr[j], acc[i][j], 0, 0, 0);
    }
    __syncthreads();
  }

#pragma unroll
  for (int i = 0; i < 4; i++) {
    const int r0 = m0 + mw + i * 16 + ((l >> 4) << 2);
#pragma unroll
    for (int j = 0; j < 4; j++) {
      const int c = n0 + nw + j * 16 + (l & 15);
      const float bb = bias[c];
#pragma unroll
      for (int r = 0; r < 4; r++) {
        float v = acc[i][j][r] + bb;
        if (RELU) v = fmaxf(v, 0.0f);
        const size_t idx = (size_t)(r0 + r) * N + c;
        if (RESID)
          outf[idx] = resid[idx] + v;
        else
          outb[idx] = f2bf(v);
      }
    }
  }
}

// ---------------- K pack: qkv K-cols -> Kp[bh][t][d] (contiguous 8KB tiles) -------
__global__ __launch_bounds__(256)
void kpack_kernel(const u16* __restrict__ QKV, u16* __restrict__ Kp) {
  const int id = blockIdx.x * 256 + threadIdx.x;   // [0, 1M) 16B chunks
  const int d8 = id & 7;
  const int t  = (id >> 3) & 2047;
  const int bh = id >> 14;
  const int bb = bh >> 4, hh = bh & 15;
  const bf16x8 v = *(const bf16x8*)(QKV + (size_t)(bb * 2048 + t) * 3072 + 1024 + hh * 64 + d8 * 8);
  *(bf16x8*)(Kp + ((size_t)bh * 2048 + t) * 64 + d8 * 8) = v;
}

// ---------------- V pack transposed: qkv V-cols -> Vp[bh][jt][d][kk] --------------
__global__ __launch_bounds__(256)
void vpack_kernel(const u16* __restrict__ QKV, u16* __restrict__ Vp) {
  __shared__ u16 tile[32][33];
  const int t0 = blockIdx.x * 32;
  const int d0 = blockIdx.y * 32;
  const int bh = blockIdx.z;
  const int bb = bh >> 4, hh = bh & 15;
  const int c = threadIdx.x & 31, r0 = threadIdx.x >> 5;
#pragma unroll
  for (int i = 0; i < 4; i++) {
    int r = r0 + i * 8;
    tile[r][c] = QKV[(size_t)(bb * 2048 + t0 + r) * 3072 + 2048 + hh * 64 + d0 + c];
  }
  __syncthreads();
#pragma unroll
  for (int i = 0; i < 4; i++) {
    int r = r0 + i * 8;   // d - d0
    Vp[(((size_t)bh * 32 + (t0 >> 6)) * 64 + d0 + r) * 64 + (t0 & 63) + c] = tile[c][r];
  }
}

// ---------------- causal flash attention: 256-row q-blocks, 8 waves, swapped ------
// All 512 blocks co-resident (2/CU). XCD-decoded 1-D grid: bh pinned per XCD for
// KV L2 locality; heavy qt first. Inner math identical to validated r3/r5 kernel.
__global__ __launch_bounds__(512, 4)
void attn_kernel(const u16* __restrict__ QKV, const u16* __restrict__ Kp,
                 const u16* __restrict__ Vp, u16* __restrict__ Y) {
  __shared__ short Ks[2][64 * 64];
  __shared__ short Vs[2][64 * 64];
  const int tid = threadIdx.x;
  const int l = tid & 63;
  const int w = tid >> 6;              // 0..7
  const int lane31 = l & 31;
  const int khalf = l >> 5;
  // XCD-aware decode: xcd = id&7 gets bh in [xcd*8, xcd*8+8), qt descending
  const int id = blockIdx.x;
  const int xcd = id & 7, s = id >> 3;
  const int bh = xcd * 8 + (s & 7);
  const int qt = 7 - (s >> 3);
  const int bb = bh >> 4, hh = bh & 15;
  const size_t baseT = (size_t)bb * 2048;
  const int qrel = qt * 256 + w * 32 + lane31;
  const size_t qrow = baseT + qrel;
  const int wave_qmin = qt * 256 + w * 32;
  const int myqmax = wave_qmin + 31;

  // Q fragments (B-operand), hoisted: q = lane31, k = s*16 + khalf*8 + e
  bf16x8 qf[4];
  {
    const u16* qp = QKV + qrow * 3072 + hh * 64 + khalf * 8;
#pragma unroll
    for (int si = 0; si < 4; si++) qf[si] = *(const bf16x8*)(qp + si * 16);
  }

  const u16* KpB = Kp + (size_t)bh * 131072;   // [2048][64]
  const u16* VpB = Vp + (size_t)bh * 131072;   // [32][64][64]

  f32x16 yac0, yac1;   // Y^T basis: d = (reg&3)+8*(reg>>2)+4*khalf (+32), q = lane31
#pragma unroll
  for (int i = 0; i < 16; i++) { yac0[i] = 0.f; yac1[i] = 0.f; }
  float m_ = -INFINITY, s_ = 0.f;

  auto stage = [&](int j, int buf) {
    const int row = tid >> 3, cb = tid & 7;          // 512 chunks each of K,V
    const int cbs = (cb ^ (row & 7)) * 8;            // pre-swizzled source (rule 21)
    const size_t toff = (size_t)j * 4096;
    gload16(KpB + toff + row * 64 + cbs, &Ks[buf][(w * 64) * 8]);
    gload16(VpB + toff + row * 64 + cbs, &Vs[buf][(w * 64) * 8]);
  };

  const int jmax = 4 * qt + 3;
  stage(0, 0);
  __syncthreads();
  int cur = 0;
  for (int j = 0; j <= jmax; ++j) {
    if (j < jmax) stage(j + 1, cur ^ 1);
    if (j * 64 <= myqmax) {   // wave-uniform gate: skip fully-masked tiles
      const short* Kc = Ks[cur];
      const short* Vc = Vs[cur];

      // ---- QK^T (swapped): S[k][q] ----
      f32x16 sa0, sa1;
#pragma unroll
      for (int i = 0; i < 16; i++) { sa0[i] = 0.f; sa1[i] = 0.f; }
      __builtin_amdgcn_s_setprio(1);
#pragma unroll
      for (int si = 0; si < 4; si++) {
        int cb = ((si * 2 + khalf) ^ (l & 7)) * 8;   // swizzled read
        bf16x8 k0 = *(const bf16x8*)(Kc + lane31 * 64 + cb);
        bf16x8 k1 = *(const bf16x8*)(Kc + (32 + lane31) * 64 + cb);
        sa0 = __builtin_amdgcn_mfma_f32_32x32x16_bf16(k0, qf[si], sa0, 0, 0, 0);
        sa1 = __builtin_amdgcn_mfma_f32_32x32x16_bf16(k1, qf[si], sa1, 0, 0, 0);
      }
      __builtin_amdgcn_s_setprio(0);

      // ---- mask + online softmax (lane-local rows, partner = l^32), log2 domain --
      float p0[16], p1[16];
      float tmax = -INFINITY;
      const bool bnd = (j * 64 + 63 > wave_qmin);
#pragma unroll
      for (int r = 0; r < 16; r++) {
        float v0 = sa0[r], v1 = sa1[r];
        if (bnd) {
          int kg = j * 64 + 4 * khalf + (r & 3) + 8 * (r >> 2);
          if (kg > qrel) v0 = -INFINITY;
          if (kg + 32 > qrel) v1 = -INFINITY;
        }
        p0[r] = v0; p1[r] = v1;
        tmax = fmaxf(tmax, fmaxf(v0, v1));
      }
      tmax = fmaxf(tmax, __shfl_xor(tmax, 32));
      // defer-max (T13): rescale only when running max moved by > 8 (2^8 headroom)
      if (!__all(tmax - m_ <= 8.0f)) {
        const float nm = fmaxf(m_, tmax);
        const float alpha = exp2f(m_ - nm);
        m_ = nm;
        s_ *= alpha;
#pragma unroll
        for (int i = 0; i < 16; i++) { yac0[i] *= alpha; yac1[i] *= alpha; }
      }
      float sum = 0.f;
#pragma unroll
      for (int r = 0; r < 16; r++) {
        p0[r] = exp2f(p0[r] - m_);
        p1[r] = exp2f(p1[r] - m_);
        sum += p0[r] + p1[r];
      }
      sum += __shfl_xor(sum, 32);
      s_ += sum;

      // ---- pack P to bf16 dwords ----
      uint32_t pk0[8], pk1[8];
#pragma unroll
      for (int jj = 0; jj < 4; jj++) {
        int rb = 4 * jj;
        uint32_t a, b;
        asm("v_cvt_pk_bf16_f32 %0, %1, %2" : "=v"(a) : "v"(p0[rb]), "v"(p0[rb + 1]));
        asm("v_cvt_pk_bf16_f32 %0, %1, %2" : "=v"(b) : "v"(p0[rb + 2]), "v"(p0[rb + 3]));
        pk0[jj] = a; pk1[jj] = b;
      }
#pragma unroll
      for (int jj = 0; jj < 4; jj++) {
        int rb = 4 * jj;
        uint32_t a, b;
        asm("v_cvt_pk_bf16_f32 %0, %1, %2" : "=v"(a) : "v"(p1[rb]), "v"(p1[rb + 1]));
        asm("v_cvt_pk_bf16_f32 %0, %1, %2" : "=v"(b) : "v"(p1[rb + 2]), "v"(p1[rb + 3]));
        pk0[4 + jj] = a; pk1[4 + jj] = b;
      }

      // ---- PV: yac += mfma(Vt_frag, P_frag) ----
#pragma unroll
      for (int kvs = 0; kvs < 4; kvs++) {
        uint32_t x0 = pk0[2 * kvs], y0 = pk0[2 * kvs + 1];
        uint32_t x1 = pk1[2 * kvs], y1 = pk1[2 * kvs + 1];
        asm volatile("v_permlane32_swap_b32 %0, %1" : "+v"(x0), "+v"(y0));
        asm volatile("v_permlane32_swap_b32 %0, %1" : "+v"(x1), "+v"(y1));
        union { uint32_t u[4]; bf16x8 v; } pf;
        pf.u[0] = x0; pf.u[1] = x1; pf.u[2] = y0; pf.u[3] = y1;
        int cb = ((kvs * 2 + khalf) ^ (l & 7)) * 8;
        bf16x8 v0 = *(const bf16x8*)(Vc + lane31 * 64 + cb);
        bf16x8 v1 = *(const bf16x8*)(Vc + (32 + lane31) * 64 + cb);
        __builtin_amdgcn_s_setprio(1);
        yac0 = __builtin_amdgcn_mfma_f32_32x32x16_bf16(v0, pf.v, yac0, 0, 0, 0);
        yac1 = __builtin_amdgcn_mfma_f32_32x32x16_bf16(v1, pf.v, yac1, 0, 0, 0);
        __builtin_amdgcn_s_setprio(0);
      }
    }
    __syncthreads();
    cur ^= 1;
  }

  // ---- epilogue: Y[q][d] = yac/s ----
  const float sinv = 1.0f / s_;
  u16* yp = Y + qrow * 1024 + hh * 64;
#pragma unroll
  for (int rq = 0; rq < 4; rq++) {
    u16x4 o0, o1;
#pragma unroll
    for (int e = 0; e < 4; e++) {
      o0[e] = f2bf(yac0[rq * 4 + e] * sinv);
      o1[e] = f2bf(yac1[rq * 4 + e] * sinv);
    }
    *(u16x4*)(yp + 8 * rq + 4 * khalf) = o0;
    *(u16x4*)(yp + 32 + 8 * rq + 4 * khalf) = o1;
  }
}

extern "C" void kernel_launch(void* const* d_in, const int* in_sizes, int n_in,
                              void* d_out, int out_size, void* d_ws, size_t ws_size,
                              hipStream_t stream) {
  const float* x    = (const float*)d_in[0];
  const float* ln1w = (const float*)d_in[1];
  const float* ln1b = (const float*)d_in[2];
  const float* Wq   = (const float*)d_in[3];
  const float* bq   = (const float*)d_in[4];
  const float* Wk   = (const float*)d_in[5];
  const float* bk   = (const float*)d_in[6];
  const float* Wv   = (const float*)d_in[7];
  const float* bv   = (const float*)d_in[8];
  const float* Wo   = (const float*)d_in[9];
  const float* bo   = (const float*)d_in[10];
  const float* ln2w = (const float*)d_in[11];
  const float* ln2b = (const float*)d_in[12];
  const float* W1   = (const float*)d_in[13];
  const float* b1   = (const float*)d_in[14];
  const float* W2   = (const float*)d_in[15];
  const float* b2   = (const float*)d_in[16];
  float* out = (float*)d_out;
  char* ws = (char*)d_ws;
  const size_t MB = 1ull << 20;
  const float SC = 0.125f * 1.44269504088896340736f;  // 1/sqrt(64) * log2(e)

  u16* h     = (u16*)(ws);              // [0,16) LN1 out
  u16* qkv   = (u16*)(ws + 16 * MB);    // [16,64) fused QKV out [8192][3072]
  u16* ff1   = (u16*)(ws);              // [0,64) overlay (h,qkv dead by FF1)
  u16* Kp    = (u16*)(ws + 64 * MB);    // [64,80) packed K [64][2048][64]
  u16* Vp    = (u16*)(ws + 80 * MB);    // [80,96) packed V^T tiles [64][32][64][64]
  float* x1  = (float*)(ws + 64 * MB);  // [64,96) post-attn residual (Kp/Vp dead)
  u16* y     = (u16*)(ws + 96 * MB);    // [96,112) attn out; reused as LN2 out
  u16* Wqkvt = (u16*)(ws + 112 * MB);   // [112,118) Wq|Wk|Wv transposed [3072][1024]
  u16* Wot   = (u16*)(ws + 118 * MB);   // [118,120)
  u16* W1t   = (u16*)(ws + 120 * MB);   // [120,128) [4096,1024]
  u16* W2t   = (u16*)(ws + 128 * MB);   // [128,136) [1024,4096]
  float* bqkv = (float*)(ws + 136 * MB);

  dim3 tb(256);
  wconv_kernel<<<dim3(32, 32), tb, 0, stream>>>(Wq, Wqkvt, 1024, 1024, SC);
  wconv_kernel<<<dim3(32, 32), tb, 0, stream>>>(Wk, Wqkvt + (1024u * 1024), 1024, 1024, 1.0f);
  wconv_kernel<<<dim3(32, 32), tb, 0, stream>>>(Wv, Wqkvt + (2048u * 1024), 1024, 1024, 1.0f);
  wconv_kernel<<<dim3(32, 32), tb, 0, stream>>>(Wo, Wot, 1024, 1024, 1.0f);
  wconv_kernel<<<dim3(128, 32), tb, 0, stream>>>(W1, W1t, 1024, 4096, 1.0f);
  wconv_kernel<<<dim3(32, 128), tb, 0, stream>>>(W2, W2t, 4096, 1024, 1.0f);
  bcat_kernel<<<dim3(12), tb, 0, stream>>>(bq, bk, bv, bqkv, SC);

  ln_kernel<<<8192, tb, 0, stream>>>(x, ln1w, ln1b, h);

  // fused QKV: [8192,1024] @ [3072,1024]^T -> [8192,3072]
  gemm_kernel<false, false><<<dim3(24, 64), tb, 0, stream>>>(h, Wqkvt, bqkv, nullptr, qkv, nullptr, 8192, 3072, 1024);

  kpack_kernel<<<4096, tb, 0, stream>>>(qkv, Kp);
  vpack_kernel<<<dim3(64, 2, 64), tb, 0, stream>>>(qkv, Vp);

  attn_kernel<<<512, dim3(512), 0, stream>>>(qkv, Kp, Vp, y);

  gemm_kernel<false, true><<<dim3(8, 64), tb, 0, stream>>>(y, Wot, bo, x, nullptr, x1, 8192, 1024, 1024);

  ln_kernel<<<8192, tb, 0, stream>>>(x1, ln2w, ln2b, y);

  gemm_kernel<true, false><<<dim3(32, 64), tb, 0, stream>>>(y, W1t, b1, nullptr, ff1, nullptr, 8192, 4096, 1024);

  gemm_kernel<false, true><<<dim3(8, 64), tb, 0, stream>>>(ff1, W2t, b2, x1, nullptr, out, 8192, 1024, 4096);
}